// Round 8
// baseline (109.392 us; speedup 1.0000x reference)
//
#include <hip/hip_runtime.h>
#include <hip/hip_cooperative_groups.h>
#include <math.h>

namespace cg = cooperative_groups;

#define NTOT 131072
#define NSIG 64
#define SEGL 2048
#define NIN 256

// ws layout (bytes):
//   [0, 524288)        y[131072] f32
//   [524288, 1048576)  w_all[64][2048] f32 (only [1024-D, 1024+min(D,1023)] written)
//   [1048576, 1048832) Dv[64] int
// Truncation: taps beyond |d| = 12|sigma|+4 are exp(<-72) == 0 in f32 and
// Z >= 1 (peak tap exp(0)=1), so truncation error ~1e-28 absolute.
//
// Single cooperative kernel, 512 blocks x 256 threads (2 blocks/CU, all
// co-resident; __launch_bounds__(256,2) caps VGPR at 128 to guarantee it).
// Phase A: y col bx*256+t via branch-free unroll-16 stream (R5's measured-best
//          layout); duty blocks (bx0<64) fold the MLP dot into the same loop,
//          then sigma -> truncated normalized window for segment bx0.
// grid.sync()  (device-scope fence: y, w_all, Dv visible everywhere)
// Phase B: truncated conv of the block's own 256 outputs (y slice L2-warm,
//          window staged in LDS).
__global__ __launch_bounds__(256, 2) void k_all(
    const float* __restrict__ x,  const float* __restrict__ W1,
    const float* __restrict__ b1, const float* __restrict__ W2,
    const float* __restrict__ b2, const float* __restrict__ W3,
    const float* __restrict__ b3, float* __restrict__ y,
    float* __restrict__ w_all, int* __restrict__ Dv,
    float* __restrict__ out)
{
  __shared__ float xl[NIN];
  __shared__ float sl[256];
  __shared__ float red[4];
  __shared__ float bc[2];
  __shared__ float S[2560];   // conv staging, seg coord = sbase + idx
  __shared__ float Wl[SEGL];  // conv window staging

  const int t = threadIdx.x;
  const int bx0 = (int)blockIdx.x;
  // bijective XCD swizzle: 64 consecutive 256-col chunks per XCD
  // (8 whole segments per XCD -> phase-B halo reads stay on-XCD)
  const int bx = ((bx0 & 7) << 6) | (bx0 >> 3);
  const int col = (bx << 8) + t;

  xl[t] = x[t];
  __syncthreads();

  // ================= phase A: y = x@W3 + b3 (+ duty sigma/window) =========
  const float* p = W3 + col;
  float a = b3[col];

  if (bx0 < NSIG) {
    // duty block: matvec + MLP dot in one loop (W1 rides under HBM latency)
    float am = b1[t];
    #pragma unroll 16
    for (int n = 0; n < NIN; ++n) {
      const float xv = xl[n];
      a  = fmaf(xv, p[(size_t)n * NTOT], a);
      am = fmaf(xv, W1[n * 256 + t], am);
    }
    y[col] = a;
    sl[t] = am / (1.0f + expf(-am));
    __syncthreads();

    const int seg = bx0;
    float v = sl[t] * W2[t * NSIG + seg];
    #pragma unroll
    for (int o = 32; o > 0; o >>= 1) v += __shfl_down(v, o, 64);
    const int lane = t & 63, wid = t >> 6;
    if (lane == 0) red[wid] = v;
    __syncthreads();
    if (t == 0) bc[0] = red[0] + red[1] + red[2] + red[3] + b2[seg];
    __syncthreads();
    const float sig = bc[0];

    const float inv2 = 1.0f / (2.0f * sig * sig);
    const float Df = 12.0f * fabsf(sig) + 4.0f;
    const int D = (Df >= 1024.0f) ? 1024 : (int)Df;
    const int dlo = -D;
    const int dhi = (D < 1023) ? D : 1023;
    const int cnt = dhi - dlo + 1;

    float zp = 0.0f;
    for (int i = t; i < cnt; i += 256) {
      const float d = (float)(dlo + i);
      const float e = expf(-d * d * inv2);
      w_all[seg * SEGL + 1024 + dlo + i] = e;
      zp += e;
    }
    v = zp;
    #pragma unroll
    for (int o = 32; o > 0; o >>= 1) v += __shfl_down(v, o, 64);
    if (lane == 0) red[wid] = v;
    __syncthreads();
    if (t == 0) bc[1] = red[0] + red[1] + red[2] + red[3];
    __syncthreads();
    const float iZ = 1.0f / bc[1];
    for (int i = t; i < cnt; i += 256)
      w_all[seg * SEGL + 1024 + dlo + i] *= iZ;
    if (t == 0) Dv[seg] = D;
  } else {
    // pure stream
    #pragma unroll 16
    for (int n = 0; n < NIN; ++n)
      a = fmaf(xl[n], p[(size_t)n * NTOT], a);
    y[col] = a;
  }

  // ================= grid-wide barrier =====================================
  cg::this_grid().sync();

  // ================= phase B: conv of this block's 256 outputs =============
  // out[m] = sum_d w[1024+d] * seg[m-1-d], d in [-D, min(D,1023)]
  const int seg = bx >> 3;
  const int M0 = (bx & 7) << 8;     // seg*SEGL + M0 == bx*256 == this chunk
  const int sbase = M0 - 1026;

  const int D = Dv[seg];            // block-uniform
  const int dlo = -D;
  const int dhi = (D < 1023) ? D : 1023;
  const int cnt = dhi - dlo + 1;

  for (int i = t; i < cnt; i += 256)
    Wl[1024 + dlo + i] = w_all[seg * SEGL + 1024 + dlo + i];

  // live span of S: [1025-dhi, 1281+D)
  const int ilo = 1025 - dhi;
  const int ihi = 1281 + D;
  for (int i = ilo + t; i < ihi; i += 256) {
    const int g = sbase + i;
    S[i] = (g >= 0 && g < SEGL) ? y[seg * SEGL + g] : 0.0f;
  }
  __syncthreads();

  float acc = 0.0f;
  for (int d = dlo; d <= dhi; ++d)
    acc = fmaf(Wl[1024 + d], S[t + 1025 - d], acc);  // broadcast + stride-1
  out[seg * SEGL + M0 + t] = acc;
}

// ---------------------------------------------------------------------------
extern "C" void kernel_launch(void* const* d_in, const int* in_sizes, int n_in,
                              void* d_out, int out_size, void* d_ws, size_t ws_size,
                              hipStream_t stream) {
  const float* x  = (const float*)d_in[0];
  const float* W1 = (const float*)d_in[1];
  const float* b1 = (const float*)d_in[2];
  const float* W2 = (const float*)d_in[3];
  const float* b2 = (const float*)d_in[4];
  const float* W3 = (const float*)d_in[5];
  const float* b3 = (const float*)d_in[6];
  float* out = (float*)d_out;

  char* ws = (char*)d_ws;
  float* y     = (float*)(ws);
  float* w_all = (float*)(ws + 524288);
  int*   Dv    = (int*)  (ws + 1048576);

  void* args[] = {(void*)&x, (void*)&W1, (void*)&b1, (void*)&W2, (void*)&b2,
                  (void*)&W3, (void*)&b3, (void*)&y, (void*)&w_all, (void*)&Dv,
                  (void*)&out};
  hipLaunchCooperativeKernel((void*)k_all, dim3(512), dim3(256), args, 0, stream);
}

// Round 9
// 35.893 us; speedup vs baseline: 3.0477x; 3.0477x over previous
//
#include <hip/hip_runtime.h>
#include <math.h>

#define NTOT 131072
#define NSIG 64
#define SEGL 2048
#define NIN 256

// ws layout (bytes):
//   [0, 524288)        y[131072] f32
//   [524288, 1048576)  w_all[64][2048] f32 (only [1024-D, 1024+min(D,1023)] written)
//   [1048576, 1048832) Dv[64] int
// Truncation: taps beyond |d| = 12|sigma|+4 are exp(<-72) == 0 in f32 and
// Z >= 1 (peak tap exp(0)=1), so truncation error ~1e-28 absolute.

// ---------------------------------------------------------------------------
// K1: y = x@W3 + b3. 512 blocks x 256 threads (2 blocks/CU, 8 waves/CU, all
// co-resident). Block owns 256 consecutive columns. Thread t = (row group
// g = t>>6 covering rows [64g, 64g+64), column quad q = (t&63)*4) streams
// float4 W3 loads (16B/lane, 1KB/wave-instr = 4x fewer VMEM instrs than
// scalar). Partials combined via LDS; each W3 element read exactly once.
// Duty blocks (bx0 < 64) fold the W1 dot into the SAME loop (h-quad = q,
// float4 W1 loads ride under W3's HBM latency), then sigma -> truncated
// normalized window for segment bx0.
// ---------------------------------------------------------------------------
__global__ __launch_bounds__(256) void k_y(
    const float* __restrict__ x,  const float* __restrict__ W1,
    const float* __restrict__ b1, const float* __restrict__ W2,
    const float* __restrict__ b2, const float* __restrict__ W3,
    const float* __restrict__ b3, float* __restrict__ y,
    float* __restrict__ w_all, int* __restrict__ Dv)
{
  __shared__ float xl[NIN];
  __shared__ float party[1024];   // [g][col] partial y
  __shared__ float partm[1024];   // [g][h]   partial MLP (duty only)
  __shared__ float sl[256];
  __shared__ float red[4];
  __shared__ float bc[2];

  const int t = threadIdx.x;
  const int bx0 = (int)blockIdx.x;
  // bijective XCD swizzle: 64 consecutive 256-col chunks per XCD
  const int bx = ((bx0 & 7) << 6) | (bx0 >> 3);
  const int colbase = bx << 8;
  const int g = t >> 6;          // row group
  const int q = (t & 63) << 2;   // column quad (16B aligned)

  xl[t] = x[t];
  __syncthreads();

  const float* wp = W3 + (size_t)(g << 6) * NTOT + colbase + q;
  float4 a = make_float4(0.0f, 0.0f, 0.0f, 0.0f);

  if (bx0 < NSIG) {
    // ---- duty: W3 quad + W1 quad in one loop ----
    const float* mp = W1 + (g << 6) * 256 + q;   // h = q..q+3
    float4 am = make_float4(0.0f, 0.0f, 0.0f, 0.0f);
    #pragma unroll 8
    for (int k = 0; k < 64; ++k) {
      const float xv = xl[(g << 6) + k];
      const float4 wv = *reinterpret_cast<const float4*>(wp + (size_t)k * NTOT);
      const float4 mv = *reinterpret_cast<const float4*>(mp + k * 256);
      a.x  = fmaf(xv, wv.x, a.x);  a.y  = fmaf(xv, wv.y, a.y);
      a.z  = fmaf(xv, wv.z, a.z);  a.w  = fmaf(xv, wv.w, a.w);
      am.x = fmaf(xv, mv.x, am.x); am.y = fmaf(xv, mv.y, am.y);
      am.z = fmaf(xv, mv.z, am.z); am.w = fmaf(xv, mv.w, am.w);
    }
    *reinterpret_cast<float4*>(&party[(g << 8) + q]) = a;
    *reinterpret_cast<float4*>(&partm[(g << 8) + q]) = am;
  } else {
    // ---- pure stream ----
    #pragma unroll 16
    for (int k = 0; k < 64; ++k) {
      const float xv = xl[(g << 6) + k];
      const float4 wv = *reinterpret_cast<const float4*>(wp + (size_t)k * NTOT);
      a.x = fmaf(xv, wv.x, a.x);  a.y = fmaf(xv, wv.y, a.y);
      a.z = fmaf(xv, wv.z, a.z);  a.w = fmaf(xv, wv.w, a.w);
    }
    *reinterpret_cast<float4*>(&party[(g << 8) + q]) = a;
  }
  __syncthreads();

  // ---- combine partials: thread t owns column colbase+t (stride-1 LDS) ----
  y[colbase + t] = party[t] + party[256 + t] + party[512 + t] + party[768 + t]
                   + b3[colbase + t];

  if (bx0 >= NSIG) return;

  // ---- MLP finish: s[h=t] = swish(sum_g partm + b1) ----
  const float amf = partm[t] + partm[256 + t] + partm[512 + t] + partm[768 + t]
                    + b1[t];
  sl[t] = amf / (1.0f + expf(-amf));
  __syncthreads();

  // ---- sigma = s @ W2[:,seg] + b2[seg] ----
  const int seg = bx0;
  float v = sl[t] * W2[t * NSIG + seg];
  #pragma unroll
  for (int o = 32; o > 0; o >>= 1) v += __shfl_down(v, o, 64);
  const int lane = t & 63, wid = t >> 6;
  if (lane == 0) red[wid] = v;
  __syncthreads();
  if (t == 0) bc[0] = red[0] + red[1] + red[2] + red[3] + b2[seg];
  __syncthreads();
  const float sig = bc[0];

  // ---- truncated gaussian window ----
  const float inv2 = 1.0f / (2.0f * sig * sig);
  const float Df = 12.0f * fabsf(sig) + 4.0f;
  const int D = (Df >= 1024.0f) ? 1024 : (int)Df;
  const int dlo = -D;
  const int dhi = (D < 1023) ? D : 1023;
  const int cnt = dhi - dlo + 1;

  float zp = 0.0f;
  for (int i = t; i < cnt; i += 256) {
    const float d = (float)(dlo + i);
    const float e = expf(-d * d * inv2);
    w_all[seg * SEGL + 1024 + dlo + i] = e;
    zp += e;
  }
  v = zp;
  #pragma unroll
  for (int o = 32; o > 0; o >>= 1) v += __shfl_down(v, o, 64);
  if (lane == 0) red[wid] = v;
  __syncthreads();
  if (t == 0) bc[1] = red[0] + red[1] + red[2] + red[3];
  __syncthreads();
  const float iZ = 1.0f / bc[1];
  for (int i = t; i < cnt; i += 256)
    w_all[seg * SEGL + 1024 + dlo + i] *= iZ;
  if (t == 0) Dv[seg] = D;
}

// ---------------------------------------------------------------------------
// K2: truncated "same" conv (verbatim from the 31.8us-best config).
// 512 blocks x 256 threads; block bx handles [seg*2048 + M0, +256).
// out[m] = sum_d w[1024+d] * seg[m-1-d], d in [-D, min(D,1023)]
// ---------------------------------------------------------------------------
__global__ __launch_bounds__(256) void k_conv(
    const float* __restrict__ y, const float* __restrict__ w_all,
    const int* __restrict__ Dv, float* __restrict__ out)
{
  __shared__ float S[2560];   // y slice, seg coord = sbase + idx, zero-padded
  __shared__ float Wl[SEGL];

  const int t = threadIdx.x;
  const int bx0 = (int)blockIdx.x;
  const int bx = ((bx0 & 7) << 6) | (bx0 >> 3);   // same XCD as producer
  const int seg = bx >> 3;
  const int M0 = (bx & 7) << 8;
  const int sbase = M0 - 1026;

  const int D = Dv[seg];
  const int dlo = -D;
  const int dhi = (D < 1023) ? D : 1023;
  const int cnt = dhi - dlo + 1;

  for (int i = t; i < cnt; i += 256)
    Wl[1024 + dlo + i] = w_all[seg * SEGL + 1024 + dlo + i];

  #pragma unroll
  for (int j = 0; j < 10; ++j) {
    const int i = t + j * 256;
    const int gg = sbase + i;
    S[i] = (gg >= 0 && gg < SEGL) ? y[seg * SEGL + gg] : 0.0f;
  }
  __syncthreads();

  float a = 0.0f;
  for (int d = dlo; d <= dhi; ++d)
    a = fmaf(Wl[1024 + d], S[t + 1025 - d], a);   // broadcast + stride-1
  out[seg * SEGL + M0 + t] = a;
}

// ---------------------------------------------------------------------------
extern "C" void kernel_launch(void* const* d_in, const int* in_sizes, int n_in,
                              void* d_out, int out_size, void* d_ws, size_t ws_size,
                              hipStream_t stream) {
  const float* x  = (const float*)d_in[0];
  const float* W1 = (const float*)d_in[1];
  const float* b1 = (const float*)d_in[2];
  const float* W2 = (const float*)d_in[3];
  const float* b2 = (const float*)d_in[4];
  const float* W3 = (const float*)d_in[5];
  const float* b3 = (const float*)d_in[6];
  float* out = (float*)d_out;

  char* ws = (char*)d_ws;
  float* y     = (float*)(ws);
  float* w_all = (float*)(ws + 524288);
  int*   Dv    = (int*)  (ws + 1048576);

  hipLaunchKernelGGL(k_y, dim3(512), dim3(256), 0, stream,
                     x, W1, b1, W2, b2, W3, b3, y, w_all, Dv);
  hipLaunchKernelGGL(k_conv, dim3(512), dim3(256), 0, stream,
                     y, w_all, Dv, out);
}

// Round 10
// 31.908 us; speedup vs baseline: 3.4284x; 1.1249x over previous
//
#include <hip/hip_runtime.h>
#include <math.h>

#define NTOT 131072
#define NSIG 64
#define SEGL 2048
#define NIN 256

// ws layout (bytes):
//   [0, 524288)        y[131072] f32
//   [524288, 1048576)  w_all[64][2048] f32 (only [1024-D, 1024+min(D,1023)] written)
//   [1048576, 1048832) Dv[64] int
// Truncation: taps beyond |d| = 12|sigma|+4 are exp(<-72) == 0 in f32 and
// Z >= 1 (peak tap exp(0)=1), so truncation error ~1e-28 absolute.

// ---------------------------------------------------------------------------
// K1: y = x@W3 + b3, each column ONCE (no halo). 512 blocks x 256 threads
// (2 blocks/CU, 8 waves/CU, all co-resident), thread-per-column scalar
// stream, unroll 32 (64KB in flight per CU vs 32KB at unroll 16 -- sized for
// queue-inflated HBM latency). Duty blocks (bx0 < 64) fold the MLP dot into
// the same loop, then sigma -> truncated normalized window for segment bx0.
// ---------------------------------------------------------------------------
__global__ __launch_bounds__(256) void k_y(
    const float* __restrict__ x,  const float* __restrict__ W1,
    const float* __restrict__ b1, const float* __restrict__ W2,
    const float* __restrict__ b2, const float* __restrict__ W3,
    const float* __restrict__ b3, float* __restrict__ y,
    float* __restrict__ w_all, int* __restrict__ Dv)
{
  __shared__ float xl[NIN];
  __shared__ float sl[256];
  __shared__ float red[4];
  __shared__ float bc[2];

  const int t = threadIdx.x;
  const int bx0 = (int)blockIdx.x;
  // bijective XCD swizzle: 64 consecutive 256-col chunks per XCD
  const int bx = ((bx0 & 7) << 6) | (bx0 >> 3);
  const int col = (bx << 8) + t;

  xl[t] = x[t];
  __syncthreads();

  const float* p = W3 + col;
  float a = b3[col];

  if (bx0 < NSIG) {
    // ---- duty block: matvec + MLP in one loop ----
    float am = b1[t];
    #pragma unroll 32
    for (int n = 0; n < NIN; ++n) {
      const float xv = xl[n];
      a  = fmaf(xv, p[(size_t)n * NTOT], a);
      am = fmaf(xv, W1[n * 256 + t], am);
    }
    y[col] = a;
    sl[t] = am / (1.0f + expf(-am));
    __syncthreads();

    const int seg = bx0;
    float v = sl[t] * W2[t * NSIG + seg];
    #pragma unroll
    for (int o = 32; o > 0; o >>= 1) v += __shfl_down(v, o, 64);
    const int lane = t & 63, wid = t >> 6;
    if (lane == 0) red[wid] = v;
    __syncthreads();
    if (t == 0) bc[0] = red[0] + red[1] + red[2] + red[3] + b2[seg];
    __syncthreads();
    const float sig = bc[0];

    const float inv2 = 1.0f / (2.0f * sig * sig);
    const float Df = 12.0f * fabsf(sig) + 4.0f;
    const int D = (Df >= 1024.0f) ? 1024 : (int)Df;
    const int dlo = -D;
    const int dhi = (D < 1023) ? D : 1023;
    const int cnt = dhi - dlo + 1;

    float zp = 0.0f;
    for (int i = t; i < cnt; i += 256) {
      const float d = (float)(dlo + i);
      const float e = expf(-d * d * inv2);
      w_all[seg * SEGL + 1024 + dlo + i] = e;
      zp += e;
    }
    v = zp;
    #pragma unroll
    for (int o = 32; o > 0; o >>= 1) v += __shfl_down(v, o, 64);
    if (lane == 0) red[wid] = v;
    __syncthreads();
    if (t == 0) bc[1] = red[0] + red[1] + red[2] + red[3];
    __syncthreads();
    const float iZ = 1.0f / bc[1];
    for (int i = t; i < cnt; i += 256)
      w_all[seg * SEGL + 1024 + dlo + i] *= iZ;
    if (t == 0) Dv[seg] = D;
  } else {
    // ---- pure stream ----
    #pragma unroll 32
    for (int n = 0; n < NIN; ++n)
      a = fmaf(xl[n], p[(size_t)n * NTOT], a);
    y[col] = a;
  }
}

// ---------------------------------------------------------------------------
// K2: truncated "same" conv (verbatim from the 31.8us-best config).
// 512 blocks x 256 threads; block bx handles [seg*2048 + M0, +256).
// Stages only the live y span; window read directly (block-uniform scalar).
// out[m] = sum_d w[1024+d] * seg[m-1-d], d in [-D, min(D,1023)]
// ---------------------------------------------------------------------------
__global__ __launch_bounds__(256) void k_conv(
    const float* __restrict__ y, const float* __restrict__ w_all,
    const int* __restrict__ Dv, float* __restrict__ out)
{
  __shared__ float S[2560];   // seg coord = sbase + idx

  const int t = threadIdx.x;
  const int bx0 = (int)blockIdx.x;
  const int bx = ((bx0 & 7) << 6) | (bx0 >> 3);   // same XCD as producer
  const int seg = bx >> 3;
  const int M0 = (bx & 7) << 8;
  const int sbase = M0 - 1026;

  const int D = Dv[seg];
  const int dlo = -D;
  const int dhi = (D < 1023) ? D : 1023;

  // live span of S: [1025-dhi, 1281+D)
  const int ilo = 1025 - dhi;
  const int ihi = 1281 + D;
  for (int i = ilo + t; i < ihi; i += 256) {
    const int g = sbase + i;
    S[i] = (g >= 0 && g < SEGL) ? y[seg * SEGL + g] : 0.0f;
  }
  __syncthreads();

  const float* wrow = w_all + seg * SEGL + 1024;
  float a = 0.0f;
  for (int d = dlo; d <= dhi; ++d)
    a = fmaf(wrow[d], S[t + 1025 - d], a);   // wrow[d] block-uniform
  out[seg * SEGL + M0 + t] = a;
}

// ---------------------------------------------------------------------------
extern "C" void kernel_launch(void* const* d_in, const int* in_sizes, int n_in,
                              void* d_out, int out_size, void* d_ws, size_t ws_size,
                              hipStream_t stream) {
  const float* x  = (const float*)d_in[0];
  const float* W1 = (const float*)d_in[1];
  const float* b1 = (const float*)d_in[2];
  const float* W2 = (const float*)d_in[3];
  const float* b2 = (const float*)d_in[4];
  const float* W3 = (const float*)d_in[5];
  const float* b3 = (const float*)d_in[6];
  float* out = (float*)d_out;

  char* ws = (char*)d_ws;
  float* y     = (float*)(ws);
  float* w_all = (float*)(ws + 524288);
  int*   Dv    = (int*)  (ws + 1048576);

  hipLaunchKernelGGL(k_y, dim3(512), dim3(256), 0, stream,
                     x, W1, b1, W2, b2, W3, b3, y, w_all, Dv);
  hipLaunchKernelGGL(k_conv, dim3(512), dim3(256), 0, stream,
                     y, w_all, Dv, out);
}